// Round 11
// baseline (387.777 us; speedup 1.0000x reference)
//
#include <hip/hip_runtime.h>
#include <hip/hip_bf16.h>
#include <hip/hip_fp16.h>
#include <math.h>

#define HEADS 4
#define CAP 64   // max in-degree incl. self-loop (Poisson(17) tail; clamped)

typedef _Float16 half8_t __attribute__((ext_vector_type(8)));
typedef float float4_t __attribute__((ext_vector_type(4)));

// ---------------- graph build (fixed-slot, no CSR scan) ----------------

// cnt=1 and slot0=self-loop folded into init
__global__ void init_cnt_k(int* cnt, unsigned short* slots, int N) {
    int i = blockIdx.x * blockDim.x + threadIdx.x;
    if (i < N) {
        cnt[i] = 1;
        slots[(size_t)i * CAP] = (unsigned short)i;
    }
}

// ---------------- weight transpose/convert prepasses ----------------

__global__ void cvt_w1t_k(const float* __restrict__ W1, _Float16* __restrict__ BT) {
    int k = blockIdx.x;        // 0..127
    int n = threadIdx.x;       // 0..255
    BT[n * 128 + k] = (_Float16)W1[k * 256 + n];
}

__global__ void cvt_w2t_k(const float* __restrict__ W2, _Float16* __restrict__ BT) {
    int n = blockIdx.x;        // 0..63
    int k = threadIdx.x;       // 0..255
    BT[n * 256 + k] = (_Float16)W2[k * 64 + n];
}

// ---------------- fused: edge scatter (8-wide phased MLP) ∥ MFMA GEMM1 ------

__global__ __launch_bounds__(256) void fused_scatter_gemm1_k(
    const int* __restrict__ src, const int* __restrict__ dst,
    int* __restrict__ cnt, unsigned short* __restrict__ slots, int E, int SB,
    const float* __restrict__ A,       // [M][128] fp32 (x)
    const _Float16* __restrict__ BT,   // [256][128] (W1^T)
    __half* __restrict__ hout,         // [M][256] fp16
    const float* __restrict__ avs,     // [4][64]
    const float* __restrict__ avd,
    float* __restrict__ os,            // [M][4]
    float* __restrict__ od, int M) {
    __shared__ _Float16 lds[4 * 16 * 72];   // 9 KB; per-wave 16x64 chunk (stride 72)

    if ((int)blockIdx.x < SB) {
        // ---- scatter branch: 8 edges per thread, phased for MLP ----
        int T = SB * 256;
        int t0 = blockIdx.x * 256 + threadIdx.x;
        int d[8], s[8];
        #pragma unroll
        for (int k = 0; k < 8; k++) {
            int i = t0 + k * T;
            if (i < E) { d[k] = dst[i]; s[k] = src[i]; }
            else d[k] = -1;
        }
        int p[8];
        #pragma unroll
        for (int k = 0; k < 8; k++) {
            if (d[k] >= 0) p[k] = atomicAdd(&cnt[d[k]], 1);
        }
        #pragma unroll
        for (int k = 0; k < 8; k++) {
            if (d[k] >= 0 && p[k] < CAP)
                slots[(size_t)d[k] * CAP + p[k]] = (unsigned short)s[k];
        }
        return;
    }

    // ---- GEMM1 branch ----
    int bx = blockIdx.x - SB;
    int wave = threadIdx.x >> 6;
    int lane = threadIdx.x & 63;
    int q = lane >> 4;
    int c16 = lane & 15;
    int row0 = bx * 64 + wave * 16;

    half8_t a[4];
    int ar = row0 + c16;
    bool avalid = (ar < M);
    const float* ap = A + (size_t)ar * 128;
    #pragma unroll
    for (int ks = 0; ks < 4; ks++) {
        if (avalid) {
            float4 f0 = *(const float4*)(ap + ks * 32 + q * 8);
            float4 f1 = *(const float4*)(ap + ks * 32 + q * 8 + 4);
            half8_t h;
            h[0] = (_Float16)f0.x; h[1] = (_Float16)f0.y;
            h[2] = (_Float16)f0.z; h[3] = (_Float16)f0.w;
            h[4] = (_Float16)f1.x; h[5] = (_Float16)f1.y;
            h[6] = (_Float16)f1.z; h[7] = (_Float16)f1.w;
            a[ks] = h;
        } else {
            a[ks] = (half8_t)(_Float16)0.0f;
        }
    }

    float4_t acc[16];
    #pragma unroll
    for (int ct = 0; ct < 16; ct++) acc[ct] = (float4_t)0.f;

    #pragma unroll
    for (int ks = 0; ks < 4; ks++) {
        #pragma unroll
        for (int ct = 0; ct < 16; ct++) {
            half8_t b = *(const half8_t*)(BT + (size_t)(ct * 16 + c16) * 128 + ks * 32 + q * 8);
            acc[ct] = __builtin_amdgcn_mfma_f32_16x16x32_f16(a[ks], b, acc[ct], 0, 0, 0);
        }
    }

    // alpha dot partials (head h = ct>>2, chan-in-head = (ct&3)*16 + c16)
    float psh[4][4] = {}, pdh[4][4] = {};
    #pragma unroll
    for (int ct = 0; ct < 16; ct++) {
        int h = ct >> 2;
        int cih = (ct & 3) * 16 + c16;
        float as_v = avs[h * 64 + cih];
        float ad_v = avd[h * 64 + cih];
        #pragma unroll
        for (int r = 0; r < 4; r++) {
            psh[h][r] = fmaf(acc[ct][r], as_v, psh[h][r]);
            pdh[h][r] = fmaf(acc[ct][r], ad_v, pdh[h][r]);
        }
    }
    #pragma unroll
    for (int h = 0; h < 4; h++) {
        #pragma unroll
        for (int r = 0; r < 4; r++) {
            #pragma unroll
            for (int o = 8; o >= 1; o >>= 1) {
                psh[h][r] += __shfl_down(psh[h][r], o, 16);
                pdh[h][r] += __shfl_down(pdh[h][r], o, 16);
            }
        }
    }
    if (c16 == 0) {
        #pragma unroll
        for (int r = 0; r < 4; r++) {
            int gr = row0 + q * 4 + r;
            if (gr < M) {
                #pragma unroll
                for (int h = 0; h < 4; h++) {
                    os[(size_t)gr * HEADS + h] = psh[h][r];
                    od[(size_t)gr * HEADS + h] = pdh[h][r];
                }
            }
        }
    }

    // fp16 store via per-wave chunked LDS staging (stride 72 halfs = 144 B)
    _Float16* wl = lds + wave * (16 * 72);
    #pragma unroll
    for (int chunk = 0; chunk < 4; chunk++) {
        #pragma unroll
        for (int c4 = 0; c4 < 4; c4++) {
            int ct = chunk * 4 + c4;
            #pragma unroll
            for (int r = 0; r < 4; r++) {
                wl[(q * 4 + r) * 72 + c4 * 16 + c16] = (_Float16)acc[ct][r];
            }
        }
        __syncthreads();
        #pragma unroll
        for (int pass = 0; pass < 2; pass++) {
            int idx8 = pass * 64 + lane;   // 128 half8 units (16 rows x 8)
            int row = idx8 >> 3;
            int col8 = idx8 & 7;
            int gr = row0 + row;
            if (gr < M) {
                *(half8_t*)(hout + (size_t)gr * 256 + chunk * 64 + col8 * 8) =
                    *(const half8_t*)(wl + row * 72 + col8 * 8);
            }
        }
        __syncthreads();
    }
}

// ---------------- MFMA GEMM layer 2: h2 = g1 @ W2 ----------------

__global__ __launch_bounds__(256) void mfma_gemm2_k(
    const _Float16* __restrict__ Ah,   // [M][256] fp16 (g1)
    const _Float16* __restrict__ BT,   // [64][256] (W2^T)
    __half* __restrict__ hout,         // [M][64] fp16
    const float* __restrict__ avs,     // [4][16]
    const float* __restrict__ avd,
    float* __restrict__ os,            // [M][4]
    float* __restrict__ od, int M) {
    __shared__ _Float16 lds[4 * 16 * 64];
    int wave = threadIdx.x >> 6;
    int lane = threadIdx.x & 63;
    int q = lane >> 4;
    int c16 = lane & 15;
    int row0 = blockIdx.x * 64 + wave * 16;

    half8_t a[8];
    int ar = row0 + c16;
    bool avalid = (ar < M);
    const _Float16* ap = Ah + (size_t)ar * 256;
    #pragma unroll
    for (int ks = 0; ks < 8; ks++) {
        if (avalid) a[ks] = *(const half8_t*)(ap + ks * 32 + q * 8);
        else        a[ks] = (half8_t)(_Float16)0.0f;
    }

    float4_t acc[4];
    #pragma unroll
    for (int ct = 0; ct < 4; ct++) acc[ct] = (float4_t)0.f;

    #pragma unroll
    for (int ks = 0; ks < 8; ks++) {
        #pragma unroll
        for (int ct = 0; ct < 4; ct++) {
            half8_t b = *(const half8_t*)(BT + (size_t)(ct * 16 + c16) * 256 + ks * 32 + q * 8);
            acc[ct] = __builtin_amdgcn_mfma_f32_16x16x32_f16(a[ks], b, acc[ct], 0, 0, 0);
        }
    }

    float ps[4][4], pd[4][4];
    #pragma unroll
    for (int ct = 0; ct < 4; ct++) {
        float as_v = avs[ct * 16 + c16];
        float ad_v = avd[ct * 16 + c16];
        #pragma unroll
        for (int r = 0; r < 4; r++) {
            ps[ct][r] = acc[ct][r] * as_v;
            pd[ct][r] = acc[ct][r] * ad_v;
            #pragma unroll
            for (int o = 8; o >= 1; o >>= 1) {
                ps[ct][r] += __shfl_down(ps[ct][r], o, 16);
                pd[ct][r] += __shfl_down(pd[ct][r], o, 16);
            }
        }
    }
    if (c16 == 0) {
        #pragma unroll
        for (int r = 0; r < 4; r++) {
            int gr = row0 + q * 4 + r;
            if (gr < M) {
                #pragma unroll
                for (int ct = 0; ct < 4; ct++) {
                    os[(size_t)gr * HEADS + ct] = ps[ct][r];
                    od[(size_t)gr * HEADS + ct] = pd[ct][r];
                }
            }
        }
    }

    _Float16* wl = lds + wave * (16 * 64);
    #pragma unroll
    for (int ct = 0; ct < 4; ct++) {
        #pragma unroll
        for (int r = 0; r < 4; r++) {
            wl[(q * 4 + r) * 64 + ct * 16 + c16] = (_Float16)acc[ct][r];
        }
    }
    __syncthreads();
    #pragma unroll
    for (int pass = 0; pass < 2; pass++) {
        int idx8 = pass * 64 + lane;
        int row = idx8 >> 3;
        int col8 = idx8 & 7;
        int gr = row0 + row;
        if (gr < M) {
            *(half8_t*)(hout + (size_t)gr * 64 + col8 * 8) =
                *(const half8_t*)(wl + row * 64 + col8 * 8);
        }
    }
}

// ---------------- GAT aggregation layer 1 — head-partitioned, XCD-local -----
// Wave = one (node, head): 64 channels = exactly one 128B L2 line of the
// h1 row. head = (blockIdx&7)>>1 so each head's blocks land on ~2 XCDs
// (round-robin block->XCD heuristic): each row-line is L2-filled by ~2 XCDs
// instead of ~7 -> gather fill traffic ~4x lower. Lane layout (as verified
// agg16 kernel): q=lane&15 -> channels [4q,4q+4) of head; eg=lane>>4 -> edge
// subslot (4 edges per load instruction; one full line per instruction).
// Softmax (m, den, p) computed identically in all four 16-lane subgroups.

__global__ __launch_bounds__(256) void gat_agg64_xcd_k(
    const __half* __restrict__ hsrc,  // [N, 256] fp16
    const float* __restrict__ as,     // [N, 4]
    const float* __restrict__ ad,     // [N, 4]
    const int* __restrict__ cnt,
    const unsigned short* __restrict__ slots,  // [N*CAP]
    const float* __restrict__ bias,   // [256]
    __half* __restrict__ outh,        // [N, 256] fp16 (post-ReLU g1)
    int N) {
    int t7 = blockIdx.x & 7;
    int head = t7 >> 1;
    int g = ((int)(blockIdx.x >> 3)) * 2 + (t7 & 1);   // node group (4 nodes)
    int node = g * 4 + (threadIdx.x >> 6);
    if (node >= N) return;
    int l = threadIdx.x & 63;
    int q = l & 15;       // channel quad within head
    int eg = l >> 4;      // edge subslot
    int deg = min(cnt[node], CAP);
    const unsigned short* sp = slots + (size_t)node * CAP;
    float adh = ad[(size_t)node * HEADS + head];
    float m = -INFINITY, den = 0.f;
    float4 acc = make_float4(0.f, 0.f, 0.f, 0.f);
    const __half* hbase = hsrc + head * 64 + (size_t)q * 4;
    for (int base = 0; base < deg; base += 16) {
        int cl = min(16, deg - base);
        int s = 0;
        float e = -INFINITY;
        if (q < cl) {   // je == q; identical in all 4 eg subgroups
            s = sp[base + q];
            float a = as[(size_t)s * HEADS + head] + adh;
            e = (a > 0.f) ? a : 0.2f * a;
        }
        float cmax = e;
        #pragma unroll
        for (int o = 8; o >= 1; o >>= 1) cmax = fmaxf(cmax, __shfl_xor(cmax, o));
        float m_new = fmaxf(m, cmax);
        float p = (q < cl) ? __expf(e - m_new) : 0.f;
        float sum = p;
        #pragma unroll
        for (int o = 8; o >= 1; o >>= 1) sum += __shfl_xor(sum, o);
        float sc = __expf(m - m_new);   // 0 on first chunk
        den = den * sc + sum;
        m = m_new;
        acc.x *= sc; acc.y *= sc; acc.z *= sc; acc.w *= sc;
        for (int j0 = 0; j0 < cl; j0 += 4) {
            int j = j0 + eg;
            int jc = min(j, cl - 1);
            float pj = __shfl(p, jc);
            int sj = __shfl(s, jc);
            if (j < cl) {
                uint2 raw = *(const uint2*)(hbase + (size_t)sj * 256);
                float2 f0 = __half22float2(*(__half2*)&raw.x);
                float2 f1 = __half22float2(*(__half2*)&raw.y);
                acc.x = fmaf(pj, f0.x, acc.x); acc.y = fmaf(pj, f0.y, acc.y);
                acc.z = fmaf(pj, f1.x, acc.z); acc.w = fmaf(pj, f1.y, acc.w);
            }
        }
    }
    // combine the 4 edge-subslot partials (lanes ±16, ±32 share q)
    acc.x += __shfl_xor(acc.x, 16); acc.y += __shfl_xor(acc.y, 16);
    acc.z += __shfl_xor(acc.z, 16); acc.w += __shfl_xor(acc.w, 16);
    acc.x += __shfl_xor(acc.x, 32); acc.y += __shfl_xor(acc.y, 32);
    acc.z += __shfl_xor(acc.z, 32); acc.w += __shfl_xor(acc.w, 32);
    if (eg == 0) {
        float inv = 1.f / den;   // den identical on all lanes
        float4 bv = *(const float4*)(bias + head * 64 + q * 4);
        float rx = fmaxf(fmaf(acc.x, inv, bv.x), 0.f);
        float ry = fmaxf(fmaf(acc.y, inv, bv.y), 0.f);
        float rz = fmaxf(fmaf(acc.z, inv, bv.z), 0.f);
        float rw = fmaxf(fmaf(acc.w, inv, bv.w), 0.f);
        __half2* op = (__half2*)(outh + (size_t)node * 256 + head * 64 + q * 4);
        op[0] = __floats2half2_rn(rx, ry);
        op[1] = __floats2half2_rn(rz, rw);
    }
}

// ---------------- GAT aggregation layer 2 (C=16, fp16 gather) ----------------

__global__ __launch_bounds__(256) void gat_agg16_f16_k(
    const __half* __restrict__ hsrc,  // [N, 64] fp16
    const float* __restrict__ as,
    const float* __restrict__ ad,
    const int* __restrict__ cnt,
    const unsigned short* __restrict__ slots,
    const float* __restrict__ bias,   // [64]
    float* __restrict__ out, int N) {
    int node = blockIdx.x * 4 + (threadIdx.x >> 6);
    if (node >= N) return;
    int l = threadIdx.x & 63;
    int ha = l >> 4;
    int je = l & 15;
    int q = l & 15;
    int hh = q >> 2;
    int eg = l >> 4;
    int deg = min(cnt[node], CAP);
    const unsigned short* sp = slots + (size_t)node * CAP;
    float adh = ad[(size_t)node * HEADS + ha];
    float m = -INFINITY, den = 0.f;
    float4 acc = make_float4(0.f, 0.f, 0.f, 0.f);
    for (int base = 0; base < deg; base += 16) {
        int cl = min(16, deg - base);
        int s = 0;
        float e = -INFINITY;
        if (je < cl) {
            s = sp[base + je];
            float a = as[(size_t)s * HEADS + ha] + adh;
            e = (a > 0.f) ? a : 0.2f * a;
        }
        float cmax = e;
        #pragma unroll
        for (int o = 8; o >= 1; o >>= 1) cmax = fmaxf(cmax, __shfl_xor(cmax, o));
        float m_new = fmaxf(m, cmax);
        float p = (je < cl) ? __expf(e - m_new) : 0.f;
        float sum = p;
        #pragma unroll
        for (int o = 8; o >= 1; o >>= 1) sum += __shfl_xor(sum, o);
        float sc = __expf(m - m_new);
        den = den * sc + sum;
        m = m_new;
        float sch = __shfl(sc, hh << 4);
        acc.x *= sch; acc.y *= sch; acc.z *= sch; acc.w *= sch;
        for (int j0 = 0; j0 < cl; j0 += 4) {
            int j = j0 + eg;
            int jc = min(j, cl - 1);
            float pj = __shfl(p, (hh << 4) + jc);
            int sj = __shfl(s, (hh << 4) + jc);
            if (j < cl) {
                uint2 raw = *(const uint2*)(hsrc + (size_t)sj * 64 + q * 4);
                float2 f0 = __half22float2(*(__half2*)&raw.x);
                float2 f1 = __half22float2(*(__half2*)&raw.y);
                acc.x = fmaf(pj, f0.x, acc.x); acc.y = fmaf(pj, f0.y, acc.y);
                acc.z = fmaf(pj, f1.x, acc.z); acc.w = fmaf(pj, f1.y, acc.w);
            }
        }
    }
    acc.x += __shfl_xor(acc.x, 16); acc.y += __shfl_xor(acc.y, 16);
    acc.z += __shfl_xor(acc.z, 16); acc.w += __shfl_xor(acc.w, 16);
    acc.x += __shfl_xor(acc.x, 32); acc.y += __shfl_xor(acc.y, 32);
    acc.z += __shfl_xor(acc.z, 32); acc.w += __shfl_xor(acc.w, 32);
    float denh = __shfl(den, hh << 4);
    if (eg == 0) {
        float inv = 1.f / denh;
        float4 bv = *(const float4*)(bias + q * 4);
        float4 r;
        r.x = fmaxf(fmaf(acc.x, inv, bv.x), 0.f);
        r.y = fmaxf(fmaf(acc.y, inv, bv.y), 0.f);
        r.z = fmaxf(fmaf(acc.z, inv, bv.z), 0.f);
        r.w = fmaxf(fmaf(acc.w, inv, bv.w), 0.f);
        *(float4*)(out + (size_t)node * 64 + q * 4) = r;
    }
}

// ---------------- pooling + FC ----------------

__global__ void graph_bounds_k(const int* __restrict__ batch, int N, int* __restrict__ bstart) {
    int g = threadIdx.x;
    if (g <= 64) {
        int lo = 0, hi = N;
        while (lo < hi) {
            int mid = (lo + hi) >> 1;
            if (batch[mid] < g) lo = mid + 1; else hi = mid;
        }
        bstart[g] = lo;
    }
}

__global__ void pool_zero_k(float* __restrict__ sums) {
    sums[blockIdx.x * blockDim.x + threadIdx.x] = 0.f;
}

__global__ __launch_bounds__(256) void pool_sum_k(const float* __restrict__ g2,
                                                  const int* __restrict__ batch,
                                                  float* __restrict__ sums, int N) {
    int c = threadIdx.x & 63;
    int r = threadIdx.x >> 6;
    int base = blockIdx.x * 256;
    int lim = min(base + 256, N);
    float acc = 0.f;
    int cur = -1;
    for (int n = base + r; n < lim; n += 4) {
        int g = batch[n];
        if (g != cur) {
            if (cur >= 0) atomicAdd(&sums[cur * 64 + c], acc);
            acc = 0.f;
            cur = g;
        }
        acc += g2[(size_t)n * 64 + c];
    }
    if (cur >= 0) atomicAdd(&sums[cur * 64 + c], acc);
}

__global__ void fc_k(const float* __restrict__ sums, const int* __restrict__ bstart,
                     const float* __restrict__ w, const float* __restrict__ b,
                     float* __restrict__ out) {
    int g = blockIdx.x, o = threadIdx.x;  // 32 threads
    float cnt_ = (float)max(bstart[g + 1] - bstart[g], 1);
    float inv = 1.f / cnt_;
    float acc = b[o];
    for (int k = 0; k < 64; k++) acc = fmaf(sums[g * 64 + k] * inv, w[k * 32 + o], acc);
    out[g * 32 + o] = acc;
}

// ---------------- launch ----------------

static inline size_t align_up(size_t x, size_t a) { return (x + a - 1) & ~(a - 1); }

extern "C" void kernel_launch(void* const* d_in, const int* in_sizes, int n_in,
                              void* d_out, int out_size, void* d_ws, size_t ws_size,
                              hipStream_t stream) {
    const float* x      = (const float*)d_in[0];
    const int*   ei     = (const int*)d_in[1];
    const int*   batch  = (const int*)d_in[2];
    const float* W1     = (const float*)d_in[3];
    const float* a_src1 = (const float*)d_in[4];
    const float* a_dst1 = (const float*)d_in[5];
    const float* b1     = (const float*)d_in[6];
    const float* W2     = (const float*)d_in[7];
    const float* a_src2 = (const float*)d_in[8];
    const float* a_dst2 = (const float*)d_in[9];
    const float* b2     = (const float*)d_in[10];
    const float* fc_w   = (const float*)d_in[11];
    const float* fc_b   = (const float*)d_in[12];
    float* out = (float*)d_out;

    const int N = in_sizes[2];
    const int E = in_sizes[1] / 2;
    const int F_in = in_sizes[0] / N;   // 128
    const int D1 = HEADS * 64;          // 256
    const int D2 = HEADS * 16;          // 64

    const int* src = ei;
    const int* dst = ei + E;

    char* w = (char*)d_ws;
    size_t off = 0;
    auto alloc = [&](size_t bytes) {
        size_t p = off;
        off = align_up(off + bytes, 256);
        return (void*)(w + p);
    };
    int* cnt    = (int*)alloc((size_t)N * 4);
    unsigned short* slots = (unsigned short*)alloc((size_t)N * CAP * 2);
    int* bstart = (int*)alloc(65 * 4);
    float* pooled = (float*)alloc(64 * 64 * 4);
    float* as1  = (float*)alloc((size_t)N * HEADS * 4);
    float* ad1  = (float*)alloc((size_t)N * HEADS * 4);
    float* as2  = (float*)alloc((size_t)N * HEADS * 4);
    float* ad2  = (float*)alloc((size_t)N * HEADS * 4);
    __half* h1h = (__half*)alloc((size_t)N * D1 * 2);
    __half* g1h = (__half*)alloc((size_t)N * D1 * 2);
    __half* h2h = (__half*)alloc((size_t)N * D2 * 2);
    float* g2   = (float*)alloc((size_t)N * D2 * 4);
    _Float16* w1t = (_Float16*)alloc((size_t)F_in * D1 * 2);  // [256][128]
    _Float16* w2t = (_Float16*)alloc((size_t)D1 * D2 * 2);    // [64][256]

    // --- prep ---
    init_cnt_k<<<(N + 255) / 256, 256, 0, stream>>>(cnt, slots, N);
    cvt_w1t_k<<<F_in, D1, 0, stream>>>(W1, w1t);
    cvt_w2t_k<<<D2, D1, 0, stream>>>(W2, w2t);

    // --- fused: edge scatter (8-wide phased) ∥ layer-1 GEMM ---
    const int SB = (E + 2047) / 2048;        // 8 edges per scatter thread
    const int GB = (N + 63) / 64;
    fused_scatter_gemm1_k<<<SB + GB, 256, 0, stream>>>(
        src, dst, cnt, slots, E, SB,
        x, w1t, h1h, a_src1, a_dst1, as1, ad1, N);

    // --- layer 1 aggregation (head-partitioned, XCD-local) ---
    {
        int ngroups = (N + 3) / 4;              // 4-node groups per head
        int bps = (ngroups + 1) / 2;            // blocks per (head, parity) slot
        gat_agg64_xcd_k<<<8 * bps, 256, 0, stream>>>(h1h, as1, ad1, cnt, slots, b1, g1h, N);
    }

    // --- layer 2 ---
    mfma_gemm2_k<<<(N + 63) / 64, 256, 0, stream>>>((const _Float16*)g1h, w2t, h2h,
                                                    a_src2, a_dst2, as2, ad2, N);
    gat_agg16_f16_k<<<(N + 3) / 4, 256, 0, stream>>>(h2h, as2, ad2, cnt, slots, b2, g2, N);

    // --- pool + fc ---
    graph_bounds_k<<<1, 128, 0, stream>>>(batch, N, bstart);
    pool_zero_k<<<16, 256, 0, stream>>>(pooled);
    pool_sum_k<<<(N + 255) / 256, 256, 0, stream>>>(g2, batch, pooled, N);
    fc_k<<<64, 32, 0, stream>>>(pooled, bstart, fc_w, fc_b, out);
}

// Round 12
// 320.192 us; speedup vs baseline: 1.2111x; 1.2111x over previous
//
#include <hip/hip_runtime.h>
#include <hip/hip_bf16.h>
#include <hip/hip_fp16.h>
#include <math.h>

#define HEADS 4
#define CAP 64   // max in-degree incl. self-loop (Poisson(17) tail; clamped)

typedef _Float16 half8_t __attribute__((ext_vector_type(8)));
typedef float float4_t __attribute__((ext_vector_type(4)));

// ---------------- graph build (fixed-slot, no CSR scan) ----------------

// cnt=1 and slot0=self-loop folded into init
__global__ void init_cnt_k(int* cnt, unsigned short* slots, int N) {
    int i = blockIdx.x * blockDim.x + threadIdx.x;
    if (i < N) {
        cnt[i] = 1;
        slots[(size_t)i * CAP] = (unsigned short)i;
    }
}

// ---------------- weight transpose/convert prepasses ----------------

__global__ void cvt_w1t_k(const float* __restrict__ W1, _Float16* __restrict__ BT) {
    int k = blockIdx.x;        // 0..127
    int n = threadIdx.x;       // 0..255
    BT[n * 128 + k] = (_Float16)W1[k * 256 + n];
}

__global__ void cvt_w2t_k(const float* __restrict__ W2, _Float16* __restrict__ BT) {
    int n = blockIdx.x;        // 0..63
    int k = threadIdx.x;       // 0..255
    BT[n * 256 + k] = (_Float16)W2[k * 64 + n];
}

// ---------------- fused: edge scatter (8-wide phased MLP) ∥ MFMA GEMM1 ------

__global__ __launch_bounds__(256) void fused_scatter_gemm1_k(
    const int* __restrict__ src, const int* __restrict__ dst,
    int* __restrict__ cnt, unsigned short* __restrict__ slots, int E, int SB,
    const float* __restrict__ A,       // [M][128] fp32 (x)
    const _Float16* __restrict__ BT,   // [256][128] (W1^T)
    __half* __restrict__ hout,         // [M][256] fp16
    const float* __restrict__ avs,     // [4][64]
    const float* __restrict__ avd,
    float* __restrict__ os,            // [M][4]
    float* __restrict__ od, int M) {
    __shared__ _Float16 lds[4 * 16 * 72];   // 9 KB; per-wave 16x64 chunk (stride 72)

    if ((int)blockIdx.x < SB) {
        // ---- scatter branch: 8 edges per thread, phased for MLP ----
        int T = SB * 256;
        int t0 = blockIdx.x * 256 + threadIdx.x;
        int d[8], s[8];
        #pragma unroll
        for (int k = 0; k < 8; k++) {
            int i = t0 + k * T;
            if (i < E) { d[k] = dst[i]; s[k] = src[i]; }
            else d[k] = -1;
        }
        int p[8];
        #pragma unroll
        for (int k = 0; k < 8; k++) {
            if (d[k] >= 0) p[k] = atomicAdd(&cnt[d[k]], 1);
        }
        #pragma unroll
        for (int k = 0; k < 8; k++) {
            if (d[k] >= 0 && p[k] < CAP)
                slots[(size_t)d[k] * CAP + p[k]] = (unsigned short)s[k];
        }
        return;
    }

    // ---- GEMM1 branch ----
    int bx = blockIdx.x - SB;
    int wave = threadIdx.x >> 6;
    int lane = threadIdx.x & 63;
    int q = lane >> 4;
    int c16 = lane & 15;
    int row0 = bx * 64 + wave * 16;

    half8_t a[4];
    int ar = row0 + c16;
    bool avalid = (ar < M);
    const float* ap = A + (size_t)ar * 128;
    #pragma unroll
    for (int ks = 0; ks < 4; ks++) {
        if (avalid) {
            float4 f0 = *(const float4*)(ap + ks * 32 + q * 8);
            float4 f1 = *(const float4*)(ap + ks * 32 + q * 8 + 4);
            half8_t h;
            h[0] = (_Float16)f0.x; h[1] = (_Float16)f0.y;
            h[2] = (_Float16)f0.z; h[3] = (_Float16)f0.w;
            h[4] = (_Float16)f1.x; h[5] = (_Float16)f1.y;
            h[6] = (_Float16)f1.z; h[7] = (_Float16)f1.w;
            a[ks] = h;
        } else {
            a[ks] = (half8_t)(_Float16)0.0f;
        }
    }

    float4_t acc[16];
    #pragma unroll
    for (int ct = 0; ct < 16; ct++) acc[ct] = (float4_t)0.f;

    #pragma unroll
    for (int ks = 0; ks < 4; ks++) {
        #pragma unroll
        for (int ct = 0; ct < 16; ct++) {
            half8_t b = *(const half8_t*)(BT + (size_t)(ct * 16 + c16) * 128 + ks * 32 + q * 8);
            acc[ct] = __builtin_amdgcn_mfma_f32_16x16x32_f16(a[ks], b, acc[ct], 0, 0, 0);
        }
    }

    // alpha dot partials (head h = ct>>2, chan-in-head = (ct&3)*16 + c16)
    float psh[4][4] = {}, pdh[4][4] = {};
    #pragma unroll
    for (int ct = 0; ct < 16; ct++) {
        int h = ct >> 2;
        int cih = (ct & 3) * 16 + c16;
        float as_v = avs[h * 64 + cih];
        float ad_v = avd[h * 64 + cih];
        #pragma unroll
        for (int r = 0; r < 4; r++) {
            psh[h][r] = fmaf(acc[ct][r], as_v, psh[h][r]);
            pdh[h][r] = fmaf(acc[ct][r], ad_v, pdh[h][r]);
        }
    }
    #pragma unroll
    for (int h = 0; h < 4; h++) {
        #pragma unroll
        for (int r = 0; r < 4; r++) {
            #pragma unroll
            for (int o = 8; o >= 1; o >>= 1) {
                psh[h][r] += __shfl_down(psh[h][r], o, 16);
                pdh[h][r] += __shfl_down(pdh[h][r], o, 16);
            }
        }
    }
    if (c16 == 0) {
        #pragma unroll
        for (int r = 0; r < 4; r++) {
            int gr = row0 + q * 4 + r;
            if (gr < M) {
                #pragma unroll
                for (int h = 0; h < 4; h++) {
                    os[(size_t)gr * HEADS + h] = psh[h][r];
                    od[(size_t)gr * HEADS + h] = pdh[h][r];
                }
            }
        }
    }

    // fp16 store via per-wave chunked LDS staging (stride 72 halfs = 144 B)
    _Float16* wl = lds + wave * (16 * 72);
    #pragma unroll
    for (int chunk = 0; chunk < 4; chunk++) {
        #pragma unroll
        for (int c4 = 0; c4 < 4; c4++) {
            int ct = chunk * 4 + c4;
            #pragma unroll
            for (int r = 0; r < 4; r++) {
                wl[(q * 4 + r) * 72 + c4 * 16 + c16] = (_Float16)acc[ct][r];
            }
        }
        __syncthreads();
        #pragma unroll
        for (int pass = 0; pass < 2; pass++) {
            int idx8 = pass * 64 + lane;   // 128 half8 units (16 rows x 8)
            int row = idx8 >> 3;
            int col8 = idx8 & 7;
            int gr = row0 + row;
            if (gr < M) {
                *(half8_t*)(hout + (size_t)gr * 256 + chunk * 64 + col8 * 8) =
                    *(const half8_t*)(wl + row * 72 + col8 * 8);
            }
        }
        __syncthreads();
    }
}

// ---------------- MFMA GEMM layer 2: h2 = g1 @ W2 ----------------

__global__ __launch_bounds__(256) void mfma_gemm2_k(
    const _Float16* __restrict__ Ah,   // [M][256] fp16 (g1)
    const _Float16* __restrict__ BT,   // [64][256] (W2^T)
    __half* __restrict__ hout,         // [M][64] fp16
    const float* __restrict__ avs,     // [4][16]
    const float* __restrict__ avd,
    float* __restrict__ os,            // [M][4]
    float* __restrict__ od, int M) {
    __shared__ _Float16 lds[4 * 16 * 64];
    int wave = threadIdx.x >> 6;
    int lane = threadIdx.x & 63;
    int q = lane >> 4;
    int c16 = lane & 15;
    int row0 = blockIdx.x * 64 + wave * 16;

    half8_t a[8];
    int ar = row0 + c16;
    bool avalid = (ar < M);
    const _Float16* ap = Ah + (size_t)ar * 256;
    #pragma unroll
    for (int ks = 0; ks < 8; ks++) {
        if (avalid) a[ks] = *(const half8_t*)(ap + ks * 32 + q * 8);
        else        a[ks] = (half8_t)(_Float16)0.0f;
    }

    float4_t acc[4];
    #pragma unroll
    for (int ct = 0; ct < 4; ct++) acc[ct] = (float4_t)0.f;

    #pragma unroll
    for (int ks = 0; ks < 8; ks++) {
        #pragma unroll
        for (int ct = 0; ct < 4; ct++) {
            half8_t b = *(const half8_t*)(BT + (size_t)(ct * 16 + c16) * 256 + ks * 32 + q * 8);
            acc[ct] = __builtin_amdgcn_mfma_f32_16x16x32_f16(a[ks], b, acc[ct], 0, 0, 0);
        }
    }

    float ps[4][4], pd[4][4];
    #pragma unroll
    for (int ct = 0; ct < 4; ct++) {
        float as_v = avs[ct * 16 + c16];
        float ad_v = avd[ct * 16 + c16];
        #pragma unroll
        for (int r = 0; r < 4; r++) {
            ps[ct][r] = acc[ct][r] * as_v;
            pd[ct][r] = acc[ct][r] * ad_v;
            #pragma unroll
            for (int o = 8; o >= 1; o >>= 1) {
                ps[ct][r] += __shfl_down(ps[ct][r], o, 16);
                pd[ct][r] += __shfl_down(pd[ct][r], o, 16);
            }
        }
    }
    if (c16 == 0) {
        #pragma unroll
        for (int r = 0; r < 4; r++) {
            int gr = row0 + q * 4 + r;
            if (gr < M) {
                #pragma unroll
                for (int ct = 0; ct < 4; ct++) {
                    os[(size_t)gr * HEADS + ct] = ps[ct][r];
                    od[(size_t)gr * HEADS + ct] = pd[ct][r];
                }
            }
        }
    }

    _Float16* wl = lds + wave * (16 * 64);
    #pragma unroll
    for (int ct = 0; ct < 4; ct++) {
        #pragma unroll
        for (int r = 0; r < 4; r++) {
            wl[(q * 4 + r) * 64 + ct * 16 + c16] = (_Float16)acc[ct][r];
        }
    }
    __syncthreads();
    #pragma unroll
    for (int pass = 0; pass < 2; pass++) {
        int idx8 = pass * 64 + lane;
        int row = idx8 >> 3;
        int col8 = idx8 & 7;
        int gr = row0 + row;
        if (gr < M) {
            *(half8_t*)(hout + (size_t)gr * 64 + col8 * 8) =
                *(const half8_t*)(wl + row * 64 + col8 * 8);
        }
    }
}

// ---------------- GAT aggregation layer 1 (C=64, fp16 gather, fp16 out) -----
// PROVEN R9 form: one WAVE per node; lane covers full 512B row (8 B/lane);
// 4 manually-unrolled independent row loads per step (MLP=4).

__global__ __launch_bounds__(256) void gat_agg64_f16_k(
    const __half* __restrict__ hsrc,  // [N, 256] fp16
    const float* __restrict__ as,     // [N, 4]
    const float* __restrict__ ad,     // [N, 4]
    const int* __restrict__ cnt,      // [N] degree (incl self-loop)
    const unsigned short* __restrict__ slots,  // [N*CAP]
    const float* __restrict__ bias,   // [256]
    __half* __restrict__ outh,        // [N, 256] fp16 (post-ReLU g1)
    int N) {
    int node = blockIdx.x * 4 + (threadIdx.x >> 6);
    if (node >= N) return;
    int l = threadIdx.x & 63;
    int h = l >> 4;
    int je = l & 15;
    int hb = h << 4;
    int deg = min(cnt[node], CAP);
    const unsigned short* sp = slots + (size_t)node * CAP;
    float adh = ad[(size_t)node * HEADS + h];
    float4 bv = *(const float4*)(bias + l * 4);
    float m = -INFINITY, den = 0.f;
    float4 acc = make_float4(0.f, 0.f, 0.f, 0.f);
    for (int base = 0; base < deg; base += 16) {
        int cl = min(16, deg - base);
        int s = 0;
        float e = -INFINITY;
        if (je < cl) {
            s = sp[base + je];
            float a = as[(size_t)s * HEADS + h] + adh;
            e = (a > 0.f) ? a : 0.2f * a;
        }
        float cmax = e;
        #pragma unroll
        for (int o = 8; o >= 1; o >>= 1) cmax = fmaxf(cmax, __shfl_xor(cmax, o));
        float m_new = fmaxf(m, cmax);
        float p = (je < cl) ? __expf(e - m_new) : 0.f;
        float sum = p;
        #pragma unroll
        for (int o = 8; o >= 1; o >>= 1) sum += __shfl_xor(sum, o);
        float sc = __expf(m - m_new);
        den = den * sc + sum;
        m = m_new;
        acc.x *= sc; acc.y *= sc; acc.z *= sc; acc.w *= sc;
        int j = 0;
        for (; j + 4 <= cl; j += 4) {
            float p0 = __shfl(p, hb + j),     p1 = __shfl(p, hb + j + 1);
            float p2 = __shfl(p, hb + j + 2), p3 = __shfl(p, hb + j + 3);
            int s0 = __shfl(s, hb + j),     s1 = __shfl(s, hb + j + 1);
            int s2 = __shfl(s, hb + j + 2), s3 = __shfl(s, hb + j + 3);
            uint2 r0 = *(const uint2*)(hsrc + (size_t)s0 * 256 + l * 4);
            uint2 r1 = *(const uint2*)(hsrc + (size_t)s1 * 256 + l * 4);
            uint2 r2 = *(const uint2*)(hsrc + (size_t)s2 * 256 + l * 4);
            uint2 r3 = *(const uint2*)(hsrc + (size_t)s3 * 256 + l * 4);
            float2 a0 = __half22float2(*(__half2*)&r0.x), b0 = __half22float2(*(__half2*)&r0.y);
            float2 a1 = __half22float2(*(__half2*)&r1.x), b1 = __half22float2(*(__half2*)&r1.y);
            float2 a2 = __half22float2(*(__half2*)&r2.x), b2 = __half22float2(*(__half2*)&r2.y);
            float2 a3 = __half22float2(*(__half2*)&r3.x), b3 = __half22float2(*(__half2*)&r3.y);
            acc.x = fmaf(p0, a0.x, acc.x); acc.y = fmaf(p0, a0.y, acc.y);
            acc.z = fmaf(p0, b0.x, acc.z); acc.w = fmaf(p0, b0.y, acc.w);
            acc.x = fmaf(p1, a1.x, acc.x); acc.y = fmaf(p1, a1.y, acc.y);
            acc.z = fmaf(p1, b1.x, acc.z); acc.w = fmaf(p1, b1.y, acc.w);
            acc.x = fmaf(p2, a2.x, acc.x); acc.y = fmaf(p2, a2.y, acc.y);
            acc.z = fmaf(p2, b2.x, acc.z); acc.w = fmaf(p2, b2.y, acc.w);
            acc.x = fmaf(p3, a3.x, acc.x); acc.y = fmaf(p3, a3.y, acc.y);
            acc.z = fmaf(p3, b3.x, acc.z); acc.w = fmaf(p3, b3.y, acc.w);
        }
        for (; j < cl; j++) {
            float pj = __shfl(p, hb + j);
            int sj = __shfl(s, hb + j);
            uint2 r0 = *(const uint2*)(hsrc + (size_t)sj * 256 + l * 4);
            float2 a0 = __half22float2(*(__half2*)&r0.x), b0 = __half22float2(*(__half2*)&r0.y);
            acc.x = fmaf(pj, a0.x, acc.x); acc.y = fmaf(pj, a0.y, acc.y);
            acc.z = fmaf(pj, b0.x, acc.z); acc.w = fmaf(pj, b0.y, acc.w);
        }
    }
    float inv = 1.f / den;
    float rx = fmaxf(fmaf(acc.x, inv, bv.x), 0.f);
    float ry = fmaxf(fmaf(acc.y, inv, bv.y), 0.f);
    float rz = fmaxf(fmaf(acc.z, inv, bv.z), 0.f);
    float rw = fmaxf(fmaf(acc.w, inv, bv.w), 0.f);
    __half2* op = (__half2*)(outh + (size_t)node * 256 + l * 4);
    op[0] = __floats2half2_rn(rx, ry);
    op[1] = __floats2half2_rn(rz, rw);
}

// ---------------- GAT aggregation layer 2 (C=16, fp16 gather) ----------------

__global__ __launch_bounds__(256) void gat_agg16_f16_k(
    const __half* __restrict__ hsrc,  // [N, 64] fp16
    const float* __restrict__ as,
    const float* __restrict__ ad,
    const int* __restrict__ cnt,
    const unsigned short* __restrict__ slots,
    const float* __restrict__ bias,   // [64]
    float* __restrict__ out, int N) {
    int node = blockIdx.x * 4 + (threadIdx.x >> 6);
    if (node >= N) return;
    int l = threadIdx.x & 63;
    int ha = l >> 4;
    int je = l & 15;
    int q = l & 15;
    int hh = q >> 2;
    int eg = l >> 4;
    int deg = min(cnt[node], CAP);
    const unsigned short* sp = slots + (size_t)node * CAP;
    float adh = ad[(size_t)node * HEADS + ha];
    float m = -INFINITY, den = 0.f;
    float4 acc = make_float4(0.f, 0.f, 0.f, 0.f);
    for (int base = 0; base < deg; base += 16) {
        int cl = min(16, deg - base);
        int s = 0;
        float e = -INFINITY;
        if (je < cl) {
            s = sp[base + je];
            float a = as[(size_t)s * HEADS + ha] + adh;
            e = (a > 0.f) ? a : 0.2f * a;
        }
        float cmax = e;
        #pragma unroll
        for (int o = 8; o >= 1; o >>= 1) cmax = fmaxf(cmax, __shfl_xor(cmax, o));
        float m_new = fmaxf(m, cmax);
        float p = (je < cl) ? __expf(e - m_new) : 0.f;
        float sum = p;
        #pragma unroll
        for (int o = 8; o >= 1; o >>= 1) sum += __shfl_xor(sum, o);
        float sc = __expf(m - m_new);
        den = den * sc + sum;
        m = m_new;
        float sch = __shfl(sc, hh << 4);
        acc.x *= sch; acc.y *= sch; acc.z *= sch; acc.w *= sch;
        for (int j0 = 0; j0 < cl; j0 += 4) {
            int j = j0 + eg;
            int jc = min(j, cl - 1);
            float pj = __shfl(p, (hh << 4) + jc);
            int sj = __shfl(s, (hh << 4) + jc);
            if (j < cl) {
                uint2 raw = *(const uint2*)(hsrc + (size_t)sj * 64 + q * 4);
                float2 f0 = __half22float2(*(__half2*)&raw.x);
                float2 f1 = __half22float2(*(__half2*)&raw.y);
                acc.x = fmaf(pj, f0.x, acc.x); acc.y = fmaf(pj, f0.y, acc.y);
                acc.z = fmaf(pj, f1.x, acc.z); acc.w = fmaf(pj, f1.y, acc.w);
            }
        }
    }
    acc.x += __shfl_xor(acc.x, 16); acc.y += __shfl_xor(acc.y, 16);
    acc.z += __shfl_xor(acc.z, 16); acc.w += __shfl_xor(acc.w, 16);
    acc.x += __shfl_xor(acc.x, 32); acc.y += __shfl_xor(acc.y, 32);
    acc.z += __shfl_xor(acc.z, 32); acc.w += __shfl_xor(acc.w, 32);
    float denh = __shfl(den, hh << 4);
    if (eg == 0) {
        float inv = 1.f / denh;
        float4 bv = *(const float4*)(bias + q * 4);
        float4 r;
        r.x = fmaxf(fmaf(acc.x, inv, bv.x), 0.f);
        r.y = fmaxf(fmaf(acc.y, inv, bv.y), 0.f);
        r.z = fmaxf(fmaf(acc.z, inv, bv.z), 0.f);
        r.w = fmaxf(fmaf(acc.w, inv, bv.w), 0.f);
        *(float4*)(out + (size_t)node * 64 + q * 4) = r;
    }
}

// ---------------- pooling + FC ----------------

__global__ void graph_bounds_k(const int* __restrict__ batch, int N, int* __restrict__ bstart) {
    int g = threadIdx.x;
    if (g <= 64) {
        int lo = 0, hi = N;
        while (lo < hi) {
            int mid = (lo + hi) >> 1;
            if (batch[mid] < g) lo = mid + 1; else hi = mid;
        }
        bstart[g] = lo;
    }
}

__global__ void pool_zero_k(float* __restrict__ sums) {
    sums[blockIdx.x * blockDim.x + threadIdx.x] = 0.f;
}

__global__ __launch_bounds__(256) void pool_sum_k(const float* __restrict__ g2,
                                                  const int* __restrict__ batch,
                                                  float* __restrict__ sums, int N) {
    int c = threadIdx.x & 63;
    int r = threadIdx.x >> 6;
    int base = blockIdx.x * 256;
    int lim = min(base + 256, N);
    float acc = 0.f;
    int cur = -1;
    for (int n = base + r; n < lim; n += 4) {
        int g = batch[n];
        if (g != cur) {
            if (cur >= 0) atomicAdd(&sums[cur * 64 + c], acc);
            acc = 0.f;
            cur = g;
        }
        acc += g2[(size_t)n * 64 + c];
    }
    if (cur >= 0) atomicAdd(&sums[cur * 64 + c], acc);
}

__global__ void fc_k(const float* __restrict__ sums, const int* __restrict__ bstart,
                     const float* __restrict__ w, const float* __restrict__ b,
                     float* __restrict__ out) {
    int g = blockIdx.x, o = threadIdx.x;  // 32 threads
    float cnt_ = (float)max(bstart[g + 1] - bstart[g], 1);
    float inv = 1.f / cnt_;
    float acc = b[o];
    for (int k = 0; k < 64; k++) acc = fmaf(sums[g * 64 + k] * inv, w[k * 32 + o], acc);
    out[g * 32 + o] = acc;
}

// ---------------- launch ----------------

static inline size_t align_up(size_t x, size_t a) { return (x + a - 1) & ~(a - 1); }

extern "C" void kernel_launch(void* const* d_in, const int* in_sizes, int n_in,
                              void* d_out, int out_size, void* d_ws, size_t ws_size,
                              hipStream_t stream) {
    const float* x      = (const float*)d_in[0];
    const int*   ei     = (const int*)d_in[1];
    const int*   batch  = (const int*)d_in[2];
    const float* W1     = (const float*)d_in[3];
    const float* a_src1 = (const float*)d_in[4];
    const float* a_dst1 = (const float*)d_in[5];
    const float* b1     = (const float*)d_in[6];
    const float* W2     = (const float*)d_in[7];
    const float* a_src2 = (const float*)d_in[8];
    const float* a_dst2 = (const float*)d_in[9];
    const float* b2     = (const float*)d_in[10];
    const float* fc_w   = (const float*)d_in[11];
    const float* fc_b   = (const float*)d_in[12];
    float* out = (float*)d_out;

    const int N = in_sizes[2];
    const int E = in_sizes[1] / 2;
    const int F_in = in_sizes[0] / N;   // 128
    const int D1 = HEADS * 64;          // 256
    const int D2 = HEADS * 16;          // 64

    const int* src = ei;
    const int* dst = ei + E;

    char* w = (char*)d_ws;
    size_t off = 0;
    auto alloc = [&](size_t bytes) {
        size_t p = off;
        off = align_up(off + bytes, 256);
        return (void*)(w + p);
    };
    int* cnt    = (int*)alloc((size_t)N * 4);
    unsigned short* slots = (unsigned short*)alloc((size_t)N * CAP * 2);
    int* bstart = (int*)alloc(65 * 4);
    float* pooled = (float*)alloc(64 * 64 * 4);
    float* as1  = (float*)alloc((size_t)N * HEADS * 4);
    float* ad1  = (float*)alloc((size_t)N * HEADS * 4);
    float* as2  = (float*)alloc((size_t)N * HEADS * 4);
    float* ad2  = (float*)alloc((size_t)N * HEADS * 4);
    __half* h1h = (__half*)alloc((size_t)N * D1 * 2);
    __half* g1h = (__half*)alloc((size_t)N * D1 * 2);
    __half* h2h = (__half*)alloc((size_t)N * D2 * 2);
    float* g2   = (float*)alloc((size_t)N * D2 * 4);
    _Float16* w1t = (_Float16*)alloc((size_t)F_in * D1 * 2);  // [256][128]
    _Float16* w2t = (_Float16*)alloc((size_t)D1 * D2 * 2);    // [64][256]

    // --- prep ---
    init_cnt_k<<<(N + 255) / 256, 256, 0, stream>>>(cnt, slots, N);
    cvt_w1t_k<<<F_in, D1, 0, stream>>>(W1, w1t);
    cvt_w2t_k<<<D2, D1, 0, stream>>>(W2, w2t);

    // --- fused: edge scatter (8-wide phased) ∥ layer-1 GEMM ---
    const int SB = (E + 2047) / 2048;        // 8 edges per scatter thread
    const int GB = (N + 63) / 64;
    fused_scatter_gemm1_k<<<SB + GB, 256, 0, stream>>>(
        src, dst, cnt, slots, E, SB,
        x, w1t, h1h, a_src1, a_dst1, as1, ad1, N);

    // --- layer 1 aggregation ---
    gat_agg64_f16_k<<<(N + 3) / 4, 256, 0, stream>>>(h1h, as1, ad1, cnt, slots, b1, g1h, N);

    // --- layer 2 ---
    mfma_gemm2_k<<<(N + 63) / 64, 256, 0, stream>>>((const _Float16*)g1h, w2t, h2h,
                                                    a_src2, a_dst2, as2, ad2, N);
    gat_agg16_f16_k<<<(N + 3) / 4, 256, 0, stream>>>(h2h, as2, ad2, cnt, slots, b2, g2, N);

    // --- pool + fc ---
    graph_bounds_k<<<1, 128, 0, stream>>>(batch, N, bstart);
    pool_zero_k<<<16, 256, 0, stream>>>(pooled);
    pool_sum_k<<<(N + 255) / 256, 256, 0, stream>>>(g2, batch, pooled, N);
    fc_k<<<64, 32, 0, stream>>>(pooled, bstart, fc_w, fc_b, out);
}